// Round 6
// baseline (363.983 us; speedup 1.0000x reference)
//
#include <hip/hip_runtime.h>
#include <hip/hip_bf16.h>

#define F 1024
#define B_ROWS 16384
#define KSEG 128           // per-block K segment (z in 0..7, mapped to XCD)
#define NMT 8              // M-tiles per block
#define NSTG (NMT * 2)     // BK=64 stages (2 per M-tile)

typedef short v8s __attribute__((ext_vector_type(8)));
typedef float v4f __attribute__((ext_vector_type(4)));
typedef unsigned short v8u __attribute__((ext_vector_type(8)));
typedef unsigned short ushort_t;

__device__ __forceinline__ unsigned short f2bf(float f) {
    unsigned int u = __builtin_bit_cast(unsigned int, f);
    u = (u + 0x7FFFu + ((u >> 16) & 1u)) >> 16;  // RNE
    return (unsigned short)u;
}
__device__ __forceinline__ float bf2f(unsigned short h) {
    return __builtin_bit_cast(float, (unsigned int)h << 16);
}

// async global->LDS, 16B per lane. LDS dest = wave-uniform base + lane*16.
__device__ __forceinline__ void gload_lds16(const ushort_t* g, ushort_t* l) {
    __builtin_amdgcn_global_load_lds(
        (const __attribute__((address_space(1))) unsigned int*)g,
        (__attribute__((address_space(3))) unsigned int*)l,
        16, 0, 0);
}

// Fused prep: [0,64) zero rowacc; [64,100) build A = 0.5*(W+W^T) with BOTH
// triangles coalesced via LDS transpose (the old lower-triangle scattered
// reads were 64x-amplified -> ~2GB of L2 traffic); [100,8292) convert X.
__global__ __launch_bounds__(256) void prep_kernel(
        const float* __restrict__ w, const float* __restrict__ x,
        ushort_t* __restrict__ A, ushort_t* __restrict__ Xb,
        float* __restrict__ acc) {
    __shared__ ushort_t tile[128][130];  // +2 pad: conflict-free transpose read
    const int bid = blockIdx.x;
    const int tid = threadIdx.x;
    if (bid < 64) {
        acc[bid * 256 + tid] = 0.0f;
    } else if (bid < 100) {
        // 36 upper-triangle 128x128 block-pairs (I<=J)
        int rem = bid - 64, I = 0;
        while (rem > 7 - I) { rem -= 8 - I; I++; }
        const int J = I + rem;
        // pass 1: upper elements, coalesced w reads + coalesced A[i][j] stores
        for (int it = 0; it < 64; ++it) {
            const int idx = it * 256 + tid;
            const int il = idx >> 7, jl = idx & 127;
            const int i = I * 128 + il, j = J * 128 + jl;
            unsigned short v = 0;
            if (i < j) {
                const int k = i * (F - 1) - (i * (i - 1)) / 2 + (j - i - 1);
                v = f2bf(0.5f * w[k]);
            }
            if (i <= j) A[i * F + j] = v;
            tile[il][jl] = v;
        }
        __syncthreads();
        // pass 2: transposed writes A[j][i], coalesced in il
        for (int it = 0; it < 64; ++it) {
            const int idx = it * 256 + tid;
            const int jl = idx >> 7, il = idx & 127;
            const int i = I * 128 + il, j = J * 128 + jl;
            if (i < j) A[j * F + i] = tile[il][jl];
        }
    } else {
        const int t = (bid - 100) * 256 + tid;
        const size_t idx = (size_t)t * 8;
        float4 v0 = *(const float4*)(x + idx);
        float4 v1 = *(const float4*)(x + idx + 4);
        v8u o;
        o[0] = f2bf(v0.x); o[1] = f2bf(v0.y); o[2] = f2bf(v0.z); o[3] = f2bf(v0.w);
        o[4] = f2bf(v1.x); o[5] = f2bf(v1.y); o[6] = f2bf(v1.z); o[7] = f2bf(v1.w);
        *(v8u*)(Xb + idx) = o;
    }
}

// Restructured K-loop GEMM:
//  - block owns (n, z): N-cols [n*128,+128), K-seg [z*128,+128); processes
//    NMT=8 M-tiles. B-tile (128x128 of A) staged ONCE, fragments hoisted
//    into 64 VGPRs -> no B barriers/reads in the loop.
//  - A-tiles double-buffered (2 x 16 KB): loads for stage s+1 issue at the
//    START of stage s, so the barrier's vmcnt(0) drain only sees loads that
//    already had the whole stage's MFMA to complete (prefetch in flight
//    across the barrier).
//  - z = blockIdx&7 -> XCD (round-robin heuristic): each XCD's 4MB L2 holds
//    exactly its 4MB K-slab of Xb.
// LDS: 32 KB B + 32 KB A-dbuf = 64 KB -> 2 blocks/CU.
__global__ __launch_bounds__(256, 2) void gemm_kernel(
        const ushort_t* __restrict__ Xb,   // [B_ROWS][F] bf16
        const ushort_t* __restrict__ A,    // [F][F] bf16 symmetric
        float*         __restrict__ rowacc) {
    __shared__ ushort_t Bs[4 * 4096];      // 4 units of 128x32
    __shared__ ushort_t As[2 * 2 * 4096];  // 2 bufs x 2 units

    const int f  = blockIdx.x;           // 0..1023
    const int z  = f & 7;
    const int s0 = f >> 3;
    const int n  = s0 & 7;
    const int g  = s0 >> 3;              // 0..15
    const int blockN = n * 128;
    const int kBase  = z * KSEG;
    const int mt0    = g * NMT;

    const int tid   = threadIdx.x;
    const int lane  = tid & 63;
    const int wave  = tid >> 6;
    const int waveM = wave >> 1;
    const int waveN = wave & 1;
    const int quad  = lane >> 4;
    const int l16   = lane & 15;

    const int lrow = lane >> 2;
    const int csrc = (lane & 3) ^ ((lane >> 3) & 3);  // XOR source swizzle (0-conflict, verified)
    const int swz  = quad ^ ((l16 >> 1) & 3);

    // ---- prologue: stage B (4 units) + A stage 0 (2 units) ----
    {
        const ushort_t* b0 = A + (size_t)(blockN + wave * 32 + lrow) * F + kBase + csrc * 8;
#pragma unroll
        for (int u = 0; u < 4; ++u) {
            gload_lds16(b0 + u * 32,          Bs + u * 4096 + (wave * 32) * 32);
            gload_lds16(b0 + 16 * F + u * 32, Bs + u * 4096 + (wave * 32 + 16) * 32);
        }
        const ushort_t* a0 = Xb + (size_t)(mt0 * 128 + wave * 32 + lrow) * F + kBase + csrc * 8;
#pragma unroll
        for (int u = 0; u < 2; ++u) {
            gload_lds16(a0 + u * 32,          As + u * 4096 + (wave * 32) * 32);
            gload_lds16(a0 + 16 * F + u * 32, As + u * 4096 + (wave * 32 + 16) * 32);
        }
    }
    __syncthreads();

    // hoist all B fragments into registers (4 k-units x 4 ni = 64 VGPRs)
    v8s bf[4][4];
#pragma unroll
    for (int u = 0; u < 4; ++u)
#pragma unroll
        for (int ni = 0; ni < 4; ++ni)
            bf[u][ni] = *(const v8s*)(Bs + u * 4096 + (waveN * 64 + ni * 16 + l16) * 32 + swz * 8);

    v4f acc[4][4];
#pragma unroll
    for (int i = 0; i < 4; i++)
#pragma unroll
        for (int j = 0; j < 4; j++) acc[i][j] = (v4f)(0.0f);

    for (int s = 0; s < NSTG; ++s) {
        const int p = s & 1;

        // issue next stage's A loads first (in flight across this stage)
        if (s + 1 < NSTG) {
            const int t    = s + 1;
            const int mrow = (mt0 + (t >> 1)) * 128;
            const int kcol = kBase + (t & 1) * 64;
            const ushort_t* a0 = Xb + (size_t)(mrow + wave * 32 + lrow) * F + kcol + csrc * 8;
            ushort_t* dst = As + (1 - p) * 8192;
#pragma unroll
            for (int u = 0; u < 2; ++u) {
                gload_lds16(a0 + u * 32,          dst + u * 4096 + (wave * 32) * 32);
                gload_lds16(a0 + 16 * F + u * 32, dst + u * 4096 + (wave * 32 + 16) * 32);
            }
        }

        // compute on buffer p (staged during previous stage)
        const ushort_t* src = As + p * 8192;
#pragma unroll
        for (int u = 0; u < 2; ++u) {
            v8s af[4];
#pragma unroll
            for (int mi = 0; mi < 4; ++mi)
                af[mi] = *(const v8s*)(src + u * 4096 + (waveM * 64 + mi * 16 + l16) * 32 + swz * 8);
            const int kg = p * 2 + u;  // B k-unit for this stage's columns
#pragma unroll
            for (int mi = 0; mi < 4; ++mi)
#pragma unroll
                for (int ni = 0; ni < 4; ++ni)
                    acc[mi][ni] = __builtin_amdgcn_mfma_f32_16x16x32_bf16(
                        af[mi], bf[kg][ni], acc[mi][ni], 0, 0, 0);
        }

        // end of an M-tile: fused row-dot epilogue, then reset accumulator
        if (p == 1) {
            const int mrow = (mt0 + (s >> 1)) * 128;
#pragma unroll
            for (int mi = 0; mi < 4; mi++) {
#pragma unroll
                for (int r = 0; r < 4; r++) {
                    const int b = mrow + waveM * 64 + mi * 16 + quad * 4 + r;
                    const ushort_t* xr = Xb + (size_t)b * F + blockN + waveN * 64 + l16;
                    float pv = acc[mi][0][r] * bf2f(xr[0])
                             + acc[mi][1][r] * bf2f(xr[16])
                             + acc[mi][2][r] * bf2f(xr[32])
                             + acc[mi][3][r] * bf2f(xr[48]);
                    pv += __shfl_xor(pv, 1);
                    pv += __shfl_xor(pv, 2);
                    pv += __shfl_xor(pv, 4);
                    pv += __shfl_xor(pv, 8);
                    if (l16 == 0) atomicAdd(&rowacc[b], pv);
                }
            }
#pragma unroll
            for (int i = 0; i < 4; i++)
#pragma unroll
                for (int j = 0; j < 4; j++) acc[i][j] = (v4f)(0.0f);
        }
        __syncthreads();  // drains this stage's prefetch; gates buffer swap
    }
}

__global__ void sigmoid_kernel(const float* __restrict__ acc, float* __restrict__ out) {
    int b = blockIdx.x * blockDim.x + threadIdx.x;
    out[b] = 1.0f / (1.0f + __expf(-acc[b]));
}

// Correctness fallback if workspace is too small: direct per-row computation.
__global__ void fallback_kernel(const float* __restrict__ x, const float* __restrict__ w,
                                float* __restrict__ out) {
    __shared__ float xs[F];
    __shared__ float partial[4];
    const int b = blockIdx.x;
    for (int i = threadIdx.x; i < F; i += 256) xs[i] = x[(size_t)b * F + i];
    __syncthreads();
    float s = 0.0f;
    for (int i = threadIdx.x; i < F - 1; i += 256) {
        const float xi = xs[i];
        const int kbase = i * (F - 1) - (i * (i - 1)) / 2 - i - 1;
        for (int j = i + 1; j < F; j++) s += w[kbase + j] * xi * xs[j];
    }
    for (int off = 32; off; off >>= 1) s += __shfl_down(s, off);
    if ((threadIdx.x & 63) == 0) partial[threadIdx.x >> 6] = s;
    __syncthreads();
    if (threadIdx.x == 0) {
        float t = partial[0] + partial[1] + partial[2] + partial[3];
        out[b] = 1.0f / (1.0f + __expf(-t));
    }
}

extern "C" void kernel_launch(void* const* d_in, const int* in_sizes, int n_in,
                              void* d_out, int out_size, void* d_ws, size_t ws_size,
                              hipStream_t stream) {
    const float* x = (const float*)d_in[0];
    const float* w = (const float*)d_in[1];
    float* out = (float*)d_out;

    const size_t acc_bytes = 65536;                       // 16384 fp32 (rounded)
    const size_t A_bytes   = (size_t)F * F * 2;           // 2 MiB bf16
    const size_t Xb_bytes  = (size_t)B_ROWS * F * 2;      // 32 MiB bf16
    const size_t needed = acc_bytes + A_bytes + Xb_bytes;

    if (ws_size < needed) {
        fallback_kernel<<<B_ROWS, 256, 0, stream>>>(x, w, out);
        return;
    }

    float*    acc = (float*)d_ws;
    ushort_t* A   = (ushort_t*)((char*)d_ws + acc_bytes);
    ushort_t* Xb  = (ushort_t*)((char*)d_ws + acc_bytes + A_bytes);

    // prep: 64 (acc zero) + 36 (build A, LDS-transposed) + 8192 (convert X)
    prep_kernel<<<64 + 36 + 8192, 256, 0, stream>>>(w, x, A, Xb, acc);
    gemm_kernel<<<1024, 256, 0, stream>>>(Xb, A, acc);
    sigmoid_kernel<<<B_ROWS / 256, 256, 0, stream>>>(acc, out);
}

// Round 7
// 166.327 us; speedup vs baseline: 2.1884x; 2.1884x over previous
//
#include <hip/hip_runtime.h>
#include <hip/hip_bf16.h>

#define F 1024
#define B_ROWS 16384

typedef short v8s __attribute__((ext_vector_type(8)));
typedef float v4f __attribute__((ext_vector_type(4)));
typedef unsigned short v8u __attribute__((ext_vector_type(8)));
typedef unsigned short ushort_t;

__device__ __forceinline__ unsigned short f2bf(float f) {
    unsigned int u = __builtin_bit_cast(unsigned int, f);
    u = (u + 0x7FFFu + ((u >> 16) & 1u)) >> 16;  // RNE
    return (unsigned short)u;
}

// Fragment-packed layout: chunk (grp, kg) = a 16-row x 32-col bf16 block
// stored as [lane][8 bf16] in exactly MFMA operand order:
//   lane l -> row grp*16 + (l&15), cols kg*32 + (l>>4)*8 .. +8.
// One chunk = 1 KB; fragment load = one coalesced global_load_dwordx4.

// prep: [0,64) zero rowacc; [64,576) pack B = 0.5*(W+W^T) (64x32 chunks,
// 4/block); [576,8768) pack X fp32->bf16 (1024x32 chunks, 4/block).
__global__ __launch_bounds__(256) void prep_kernel(
        const float* __restrict__ w, const float* __restrict__ x,
        ushort_t* __restrict__ Bp, ushort_t* __restrict__ Xp,
        float* __restrict__ acc) {
    const int bid  = blockIdx.x;
    const int tid  = threadIdx.x;
    const int lane = tid & 63;
    const int wave = tid >> 6;
    const int l16  = lane & 15;
    const int quad = lane >> 4;

    if (bid < 64) {
        acc[bid * 256 + tid] = 0.0f;
    } else if (bid < 576) {
        const int c  = (bid - 64) * 4 + wave;   // 0..2047
        const int i  = (c >> 5) * 16 + l16;     // A row
        const int j0 = (c & 31) * 32 + quad * 8;
        v8u o;
#pragma unroll
        for (int e = 0; e < 8; ++e) {
            const int j = j0 + e;
            float v = 0.0f;
            if (i != j) {
                const int a = min(i, j), b = max(i, j);
                const int k = a * (F - 1) - (a * (a - 1)) / 2 + (b - a - 1);
                v = 0.5f * w[k];  // scattered half is L2-resident (w = 2MB)
            }
            o[e] = f2bf(v);
        }
        *(v8u*)(Bp + (size_t)c * 512 + lane * 8) = o;
    } else {
        const int c  = (bid - 576) * 4 + wave;  // 0..32767
        const int r  = (c >> 5) * 16 + l16;     // X row
        const int k0 = (c & 31) * 32 + quad * 8;
        const float* src = x + (size_t)r * F + k0;
        float4 v0 = *(const float4*)(src);
        float4 v1 = *(const float4*)(src + 4);
        v8u o;
        o[0] = f2bf(v0.x); o[1] = f2bf(v0.y); o[2] = f2bf(v0.z); o[3] = f2bf(v0.w);
        o[4] = f2bf(v1.x); o[5] = f2bf(v1.y); o[6] = f2bf(v1.z); o[7] = f2bf(v1.w);
        *(v8u*)(Xp + (size_t)c * 512 + lane * 8) = o;
    }
}

// LDS-free GEMM: both MFMA operands loaded directly from the fragment-packed
// arrays with single coalesced 16B/lane loads -> no __syncthreads, no
// vmcnt(0) drains; the compiler software-pipelines the plain loads against
// MFMA (the AITER/flatmm regime the 2-barrier LDS loop couldn't express).
// Register software-pipeline depth 1; ALL register-array indices are
// compile-time (round-6 lesson: runtime indexing -> scratch spill).
// Block (xcd-swizzled): rows [blockM,+128), cols [blockN,+128), K z-half.
__global__ __launch_bounds__(256) void gemm_kernel(
        const ushort_t* __restrict__ Xp,   // packed X [1024][32] chunks
        const ushort_t* __restrict__ Bp,   // packed A_sym [64][32] chunks
        const float*   __restrict__ Xf,    // fp32 X (epilogue)
        float*         __restrict__ rowacc) {
    const int f   = blockIdx.x;          // 0..2047
    const int xcd = f & 7;
    const int s   = f >> 3;
    const int n   = s & 7;
    const int z   = (s >> 3) & 1;
    const int y   = s >> 4;              // 0..15
    const int blockM = (xcd * 16 + y) * 128;
    const int blockN = n * 128;
    const int kg0    = z * 16;           // 16 k-groups of 32

    const int tid   = threadIdx.x;
    const int lane  = tid & 63;
    const int wave  = tid >> 6;
    const int waveM = wave >> 1;
    const int waveN = wave & 1;
    const int quad  = lane >> 4;
    const int l16   = lane & 15;

    const int mg = (blockM >> 4) + waveM * 4;  // + mi
    const int ng = (blockN >> 4) + waveN * 4;  // + ni

    // fragment pointers (v8s units of 16B; chunk = 64 units)
    const v8s* A8 = (const v8s*)Xp + ((size_t)mg * 32 + kg0) * 64 + lane;
    const v8s* B8 = (const v8s*)Bp + ((size_t)ng * 32 + kg0) * 64 + lane;

    v4f acc[4][4];
#pragma unroll
    for (int i = 0; i < 4; i++)
#pragma unroll
        for (int j = 0; j < 4; j++) acc[i][j] = (v4f)(0.0f);

    v8s a0[4], b0[4], a1[4], b1[4];
#pragma unroll
    for (int mi = 0; mi < 4; ++mi) a0[mi] = A8[mi * 32 * 64];
#pragma unroll
    for (int ni = 0; ni < 4; ++ni) b0[ni] = B8[ni * 32 * 64];

#pragma unroll
    for (int t = 0; t < 16; t += 2) {
        if (t + 1 < 16) {
#pragma unroll
            for (int mi = 0; mi < 4; ++mi) a1[mi] = A8[(mi * 32 + t + 1) * 64];
#pragma unroll
            for (int ni = 0; ni < 4; ++ni) b1[ni] = B8[(ni * 32 + t + 1) * 64];
        }
#pragma unroll
        for (int mi = 0; mi < 4; ++mi)
#pragma unroll
            for (int ni = 0; ni < 4; ++ni)
                acc[mi][ni] = __builtin_amdgcn_mfma_f32_16x16x32_bf16(
                    a0[mi], b0[ni], acc[mi][ni], 0, 0, 0);
        if (t + 2 < 16) {
#pragma unroll
            for (int mi = 0; mi < 4; ++mi) a0[mi] = A8[(mi * 32 + t + 2) * 64];
#pragma unroll
            for (int ni = 0; ni < 4; ++ni) b0[ni] = B8[(ni * 32 + t + 2) * 64];
        }
#pragma unroll
        for (int mi = 0; mi < 4; ++mi)
#pragma unroll
            for (int ni = 0; ni < 4; ++ni)
                acc[mi][ni] = __builtin_amdgcn_mfma_f32_16x16x32_bf16(
                    a1[mi], b1[ni], acc[mi][ni], 0, 0, 0);
    }

    // Epilogue: C/D mapping (verified): col = lane&15, row = quad*4 + reg.
    // partial_b = sum_ni acc[mi][ni][r] * x[b][blockN + waveN*64 + ni*16 + l16]
#pragma unroll
    for (int mi = 0; mi < 4; mi++) {
#pragma unroll
        for (int r = 0; r < 4; r++) {
            const int b = blockM + waveM * 64 + mi * 16 + quad * 4 + r;
            const float* xr = Xf + (size_t)b * F + blockN + waveN * 64 + l16;
            float pv = acc[mi][0][r] * xr[0]
                     + acc[mi][1][r] * xr[16]
                     + acc[mi][2][r] * xr[32]
                     + acc[mi][3][r] * xr[48];
            pv += __shfl_xor(pv, 1);
            pv += __shfl_xor(pv, 2);
            pv += __shfl_xor(pv, 4);
            pv += __shfl_xor(pv, 8);
            if (l16 == 0) atomicAdd(&rowacc[b], pv);
        }
    }
}

__global__ void sigmoid_kernel(const float* __restrict__ acc, float* __restrict__ out) {
    int b = blockIdx.x * blockDim.x + threadIdx.x;
    out[b] = 1.0f / (1.0f + __expf(-acc[b]));
}

// Correctness fallback if workspace is too small: direct per-row computation.
__global__ void fallback_kernel(const float* __restrict__ x, const float* __restrict__ w,
                                float* __restrict__ out) {
    __shared__ float xs[F];
    __shared__ float partial[4];
    const int b = blockIdx.x;
    for (int i = threadIdx.x; i < F; i += 256) xs[i] = x[(size_t)b * F + i];
    __syncthreads();
    float s = 0.0f;
    for (int i = threadIdx.x; i < F - 1; i += 256) {
        const float xi = xs[i];
        const int kbase = i * (F - 1) - (i * (i - 1)) / 2 - i - 1;
        for (int j = i + 1; j < F; j++) s += w[kbase + j] * xi * xs[j];
    }
    for (int off = 32; off; off >>= 1) s += __shfl_down(s, off);
    if ((threadIdx.x & 63) == 0) partial[threadIdx.x >> 6] = s;
    __syncthreads();
    if (threadIdx.x == 0) {
        float t = partial[0] + partial[1] + partial[2] + partial[3];
        out[b] = 1.0f / (1.0f + __expf(-t));
    }
}

extern "C" void kernel_launch(void* const* d_in, const int* in_sizes, int n_in,
                              void* d_out, int out_size, void* d_ws, size_t ws_size,
                              hipStream_t stream) {
    const float* x = (const float*)d_in[0];
    const float* w = (const float*)d_in[1];
    float* out = (float*)d_out;

    const size_t acc_bytes = 65536;                       // 16384 fp32 (rounded)
    const size_t B_bytes   = (size_t)F * F * 2;           // 2 MiB packed A_sym
    const size_t Xp_bytes  = (size_t)B_ROWS * F * 2;      // 32 MiB packed X
    const size_t needed = acc_bytes + B_bytes + Xp_bytes;

    if (ws_size < needed) {
        fallback_kernel<<<B_ROWS, 256, 0, stream>>>(x, w, out);
        return;
    }

    float*    acc = (float*)d_ws;
    ushort_t* Bp  = (ushort_t*)((char*)d_ws + acc_bytes);
    ushort_t* Xp  = (ushort_t*)((char*)d_ws + acc_bytes + B_bytes);

    // prep: 64 (acc zero) + 512 (pack B) + 8192 (pack X)
    prep_kernel<<<64 + 512 + 8192, 256, 0, stream>>>(w, x, Bp, Xp, acc);
    gemm_kernel<<<2048, 256, 0, stream>>>(Xp, Bp, x, acc);
    sigmoid_kernel<<<B_ROWS / 256, 256, 0, stream>>>(acc, out);
}